// Round 1
// baseline (377.416 us; speedup 1.0000x reference)
//
#include <hip/hip_runtime.h>

#define D_FEAT 64

__global__ void degree_kernel(const int* __restrict__ src, const int* __restrict__ dst,
                              int* __restrict__ deg_src, int* __restrict__ deg_dst, int E) {
    int e = blockIdx.x * blockDim.x + threadIdx.x;
    if (e < E) {
        atomicAdd(&deg_src[src[e]], 1);
        atomicAdd(&deg_dst[dst[e]], 1);
    }
}

__global__ void norm_kernel(const int* __restrict__ deg_src, const int* __restrict__ deg_dst,
                            float* __restrict__ norm_src, float* __restrict__ norm_dst, int N) {
    int i = blockIdx.x * blockDim.x + threadIdx.x;
    if (i < N) {
        float ds = (float)max(deg_src[i], 1);
        float dd = (float)max(deg_dst[i], 1);
        norm_src[i] = 1.0f / sqrtf(ds);
        norm_dst[i] = 1.0f / sqrtf(dd);
    }
}

// One 64-lane wave per edge: lane f handles feature dim f.
// out[dst] += feat[src] * norm_src[src] * norm_dst[dst]  (norm_dst folded in,
// valid because the post-scale is linear over the segment sum).
__global__ void scatter_kernel(const float* __restrict__ feat,
                               const int* __restrict__ src, const int* __restrict__ dst,
                               const float* __restrict__ norm_src,
                               const float* __restrict__ norm_dst,
                               float* __restrict__ out, int E) {
    int e = blockIdx.x * (blockDim.x >> 6) + (threadIdx.x >> 6);
    int lane = threadIdx.x & 63;
    if (e >= E) return;
    int s = src[e];
    int d = dst[e];
    float c = norm_src[s] * norm_dst[d];          // wave-uniform (broadcast loads)
    float v = feat[(size_t)s * D_FEAT + lane] * c; // coalesced 256B per wave
    atomicAdd(&out[(size_t)d * D_FEAT + lane], v); // coalesced 256B atomic burst
}

extern "C" void kernel_launch(void* const* d_in, const int* in_sizes, int n_in,
                              void* d_out, int out_size, void* d_ws, size_t ws_size,
                              hipStream_t stream) {
    const float* feat = (const float*)d_in[0];
    const int*   src  = (const int*)d_in[1];
    const int*   dst  = (const int*)d_in[2];
    float* out = (float*)d_out;

    const int E = in_sizes[1];
    const int N = in_sizes[0] / D_FEAT;

    int*   deg_src  = (int*)d_ws;
    int*   deg_dst  = deg_src + N;
    float* norm_src = (float*)(deg_dst + N);
    float* norm_dst = norm_src + N;

    hipMemsetAsync(deg_src, 0, (size_t)2 * N * sizeof(int), stream);
    hipMemsetAsync(out, 0, (size_t)out_size * sizeof(float), stream);

    degree_kernel<<<(E + 255) / 256, 256, 0, stream>>>(src, dst, deg_src, deg_dst, E);
    norm_kernel<<<(N + 255) / 256, 256, 0, stream>>>(deg_src, deg_dst, norm_src, norm_dst, N);

    // 4 edges (4 waves) per 256-thread block
    const int epb = 4;
    scatter_kernel<<<(E + epb - 1) / epb, 256, 0, stream>>>(feat, src, dst,
                                                            norm_src, norm_dst, out, E);
}

// Round 2
// 288.431 us; speedup vs baseline: 1.3085x; 1.3085x over previous
//
#include <hip/hip_runtime.h>

#define D_FEAT 64
#define SCAN_BLK 256

// ---------------- degree count (int atomics, low contention) ----------------
__global__ void degree_kernel(const int* __restrict__ src, const int* __restrict__ dst,
                              int* __restrict__ deg_src, int* __restrict__ deg_dst, int E) {
    int e = blockIdx.x * blockDim.x + threadIdx.x;
    if (e < E) {
        atomicAdd(&deg_src[src[e]], 1);
        atomicAdd(&deg_dst[dst[e]], 1);
    }
}

// ---------------- norms ----------------
__global__ void norm_kernel(const int* __restrict__ deg_src, const int* __restrict__ deg_dst,
                            float* __restrict__ norm_src, float* __restrict__ norm_dst, int N) {
    int i = blockIdx.x * blockDim.x + threadIdx.x;
    if (i < N) {
        norm_src[i] = 1.0f / sqrtf((float)max(deg_src[i], 1));
        norm_dst[i] = 1.0f / sqrtf((float)max(deg_dst[i], 1));
    }
}

// ---------------- 2-level exclusive scan of deg_dst -> row_start ----------------
// pass 1: per-block (256-wide) totals
__global__ void block_sum_kernel(const int* __restrict__ deg, int* __restrict__ blk_sums, int N) {
    int t = threadIdx.x;
    int i = blockIdx.x * SCAN_BLK + t;
    int v = (i < N) ? deg[i] : 0;
    #pragma unroll
    for (int off = 32; off >= 1; off >>= 1) v += __shfl_down(v, off);
    __shared__ int ws4[SCAN_BLK / 64];
    if ((t & 63) == 0) ws4[t >> 6] = v;
    __syncthreads();
    if (t == 0) blk_sums[blockIdx.x] = ws4[0] + ws4[1] + ws4[2] + ws4[3];
}

// pass 2: exclusive scan of block sums (nblk <= 1024, single block)
__global__ void scan_blk_sums_kernel(int* __restrict__ blk_sums, int nblk) {
    __shared__ int lds[1024];
    int t = threadIdx.x;
    int v = (t < nblk) ? blk_sums[t] : 0;
    lds[t] = v;
    __syncthreads();
    for (int off = 1; off < 1024; off <<= 1) {
        int x = (t >= off) ? lds[t - off] : 0;
        __syncthreads();
        lds[t] += x;
        __syncthreads();
    }
    if (t < nblk) blk_sums[t] = lds[t] - v;  // exclusive = inclusive - self
}

// pass 3: local exclusive scan + block offset
__global__ void row_start_kernel(const int* __restrict__ deg, const int* __restrict__ blk_sums,
                                 int* __restrict__ row_start, int N) {
    __shared__ int lds[SCAN_BLK];
    int t = threadIdx.x;
    int i = blockIdx.x * SCAN_BLK + t;
    int v = (i < N) ? deg[i] : 0;
    lds[t] = v;
    __syncthreads();
    for (int off = 1; off < SCAN_BLK; off <<= 1) {
        int x = (t >= off) ? lds[t - off] : 0;
        __syncthreads();
        lds[t] += x;
        __syncthreads();
    }
    if (i < N) row_start[i] = lds[t] - v + blk_sums[blockIdx.x];
}

// ---------------- counting-sort placement: group edges by dst ----------------
__global__ void place_kernel(const int* __restrict__ src, const int* __restrict__ dst,
                             const float* __restrict__ norm_src,
                             const int* __restrict__ row_start, int* __restrict__ cursor,
                             int* __restrict__ sorted_src, float* __restrict__ sorted_coef,
                             int E) {
    int e = blockIdx.x * blockDim.x + threadIdx.x;
    if (e >= E) return;
    int s = src[e], d = dst[e];
    int pos = row_start[d] + atomicAdd(&cursor[d], 1);
    sorted_src[pos]  = s;
    sorted_coef[pos] = norm_src[s];   // pre-fold source norm into the edge
}

// ---------------- deterministic gather-aggregate: one wave per node ----------------
__global__ void aggregate_kernel(const float* __restrict__ feat,
                                 const int* __restrict__ sorted_src,
                                 const float* __restrict__ sorted_coef,
                                 const int* __restrict__ row_start,
                                 const int* __restrict__ deg_dst,
                                 const float* __restrict__ norm_dst,
                                 float* __restrict__ out, int N) {
    int node = blockIdx.x * (blockDim.x >> 6) + (threadIdx.x >> 6);
    int lane = threadIdx.x & 63;
    if (node >= N) return;
    int k    = deg_dst[node];
    int base = row_start[node];
    float acc = 0.0f;
    for (int i0 = 0; i0 < k; i0 += 64) {
        int kk = min(64, k - i0);
        int   s = 0;
        float c = 0.0f;
        if (lane < kk) {
            s = sorted_src[base + i0 + lane];
            c = sorted_coef[base + i0 + lane];
        }
        // broadcast each edge across the wave; feature row load is coalesced 256B
        for (int j = 0; j < kk; ++j) {
            int   sj = __shfl(s, j);
            float cj = __shfl(c, j);
            acc += feat[(size_t)sj * D_FEAT + lane] * cj;
        }
    }
    out[(size_t)node * D_FEAT + lane] = acc * norm_dst[node];
}

extern "C" void kernel_launch(void* const* d_in, const int* in_sizes, int n_in,
                              void* d_out, int out_size, void* d_ws, size_t ws_size,
                              hipStream_t stream) {
    const float* feat = (const float*)d_in[0];
    const int*   src  = (const int*)d_in[1];
    const int*   dst  = (const int*)d_in[2];
    float* out = (float*)d_out;

    const int E = in_sizes[1];
    const int N = in_sizes[0] / D_FEAT;
    const int nblk = (N + SCAN_BLK - 1) / SCAN_BLK;   // 391 for N=100k (must be <=1024)

    // workspace layout (~10.4 MB)
    int*   deg_src     = (int*)d_ws;                  // N
    int*   deg_dst     = deg_src + N;                 // N
    int*   cursor      = deg_dst + N;                 // N
    int*   row_start   = cursor + N;                  // N
    int*   blk_sums    = row_start + N;               // 1024
    float* norm_src    = (float*)(blk_sums + 1024);   // N
    float* norm_dst    = norm_src + N;                // N
    int*   sorted_src  = (int*)(norm_dst + N);        // E
    float* sorted_coef = (float*)(sorted_src + E);    // E

    // zero the three counter arrays in one memset (contiguous)
    hipMemsetAsync(deg_src, 0, (size_t)3 * N * sizeof(int), stream);

    degree_kernel<<<(E + 255) / 256, 256, 0, stream>>>(src, dst, deg_src, deg_dst, E);
    norm_kernel<<<(N + 255) / 256, 256, 0, stream>>>(deg_src, deg_dst, norm_src, norm_dst, N);

    block_sum_kernel<<<nblk, SCAN_BLK, 0, stream>>>(deg_dst, blk_sums, N);
    scan_blk_sums_kernel<<<1, 1024, 0, stream>>>(blk_sums, nblk);
    row_start_kernel<<<nblk, SCAN_BLK, 0, stream>>>(deg_dst, blk_sums, row_start, N);

    place_kernel<<<(E + 255) / 256, 256, 0, stream>>>(src, dst, norm_src, row_start, cursor,
                                                      sorted_src, sorted_coef, E);

    // 4 nodes (4 waves) per 256-thread block; out fully overwritten (no memset needed)
    aggregate_kernel<<<(N + 3) / 4, 256, 0, stream>>>(feat, sorted_src, sorted_coef,
                                                      row_start, deg_dst, norm_dst, out, N);
}